// Round 3
// baseline (370.303 us; speedup 1.0000x reference)
//
#include <hip/hip_runtime.h>

#define NEG_INF (-1.0e30f)
#define CAP 4096          // candidate buffer capacity (expected ~230 for this data)
#define NBKT 4096         // 12-bit histogram buckets

__device__ __forceinline__ unsigned flip(float f) {
    // order-preserving map: larger float -> larger uint
    unsigned u = __float_as_uint(f);
    return (u & 0x80000000u) ? ~u : (u | 0x80000000u);
}

__device__ __forceinline__ bool pair_gt(float sa, int ia, float sb, int ib) {
    // descending score, ascending index on ties (matches jax.lax.top_k)
    return (sa > sb) || (sa == sb && ia < ib);
}

// ---------------- Pass 1: pure GEMV, scores[i] = emb[i] . emb[q] ----------------
// 4 lanes x 4 float4 cover one 256B row: 4 independent loads/thread/row,
// reduction = 2 quad_perm DPP shuffles (no LDS pipe). Unroll x2 -> 8 loads in flight.
__global__ __launch_bounds__(256) void k_gemv(const float* __restrict__ emb,
                                              const int* __restrict__ p_idx,
                                              int n_items,
                                              float* __restrict__ scores) {
    const int tid   = threadIdx.x;
    const int lane4 = tid & 3;
    const int rowg  = tid >> 2;            // 0..63: row within block half
    const float4* up = (const float4*)(emb + (size_t)(*p_idx) * 64);
    const float4 u0 = up[lane4];
    const float4 u1 = up[lane4 + 4];
    const float4 u2 = up[lane4 + 8];
    const float4 u3 = up[lane4 + 12];

    const int item_a = blockIdx.x * 128 + rowg;
    const int item_b = item_a + 64;

    float pa = NEG_INF, pb = NEG_INF;
    if (item_a < n_items) {
        const float4* rp = (const float4*)(emb + (size_t)item_a * 64);
        const float4 v0 = rp[lane4], v1 = rp[lane4 + 4], v2 = rp[lane4 + 8], v3 = rp[lane4 + 12];
        float q0 = v0.x*u0.x + v0.y*u0.y + v0.z*u0.z + v0.w*u0.w;
        float q1 = v1.x*u1.x + v1.y*u1.y + v1.z*u1.z + v1.w*u1.w;
        float q2 = v2.x*u2.x + v2.y*u2.y + v2.z*u2.z + v2.w*u2.w;
        float q3 = v3.x*u3.x + v3.y*u3.y + v3.z*u3.z + v3.w*u3.w;
        pa = (q0 + q1) + (q2 + q3);
    }
    if (item_b < n_items) {
        const float4* rp = (const float4*)(emb + (size_t)item_b * 64);
        const float4 v0 = rp[lane4], v1 = rp[lane4 + 4], v2 = rp[lane4 + 8], v3 = rp[lane4 + 12];
        float q0 = v0.x*u0.x + v0.y*u0.y + v0.z*u0.z + v0.w*u0.w;
        float q1 = v1.x*u1.x + v1.y*u1.y + v1.z*u1.z + v1.w*u1.w;
        float q2 = v2.x*u2.x + v2.y*u2.y + v2.z*u2.z + v2.w*u2.w;
        float q3 = v3.x*u3.x + v3.y*u3.y + v3.z*u3.z + v3.w*u3.w;
        pb = (q0 + q1) + (q2 + q3);
    }
    // width-4 butterfly: lowers to DPP quad_perm (VALU), not ds_bpermute
    pa += __shfl_xor(pa, 1, 4);  pa += __shfl_xor(pa, 2, 4);
    pb += __shfl_xor(pb, 1, 4);  pb += __shfl_xor(pb, 2, 4);
    if (lane4 == 0) {
        if (item_a < n_items) scores[item_a] = pa;   // active lanes write consecutive 4B
        if (item_b < n_items) scores[item_b] = pb;
    }
}

// ---------------- Pass 2: 4096-bucket histogram of key top-12-bits ----------------
__global__ __launch_bounds__(256) void k_hist(const float* __restrict__ scores,
                                              int n4, unsigned* __restrict__ hist) {
    __shared__ unsigned h[NBKT];
    const int tid = threadIdx.x;
    for (int i = tid; i < NBKT; i += 256) h[i] = 0;
    __syncthreads();
    const float4* s4 = (const float4*)scores;
    for (int i = blockIdx.x * 256 + tid; i < n4; i += gridDim.x * 256) {
        float4 v = s4[i];
        atomicAdd(&h[flip(v.x) >> 20], 1u);
        atomicAdd(&h[flip(v.y) >> 20], 1u);
        atomicAdd(&h[flip(v.z) >> 20], 1u);
        atomicAdd(&h[flip(v.w) >> 20], 1u);
    }
    __syncthreads();
    for (int i = tid; i < NBKT; i += 256) {
        unsigned c = h[i];
        if (c) atomicAdd(&hist[i], c);
    }
}

// ---------------- Pass 3: compact with inlined boundary-bucket selection --------
// Every block redundantly computes B (deterministic), then appends items with
// bucket >= B via global atomic.
__global__ __launch_bounds__(256) void k_compact(const float* __restrict__ scores,
                                                 int n4,
                                                 const unsigned* __restrict__ hist,
                                                 int k,
                                                 unsigned* __restrict__ cnt,
                                                 float* __restrict__ cand_s,
                                                 int* __restrict__ cand_i) {
    __shared__ unsigned h[NBKT];
    __shared__ unsigned psum[256];
    __shared__ unsigned sB;
    const int tid = threadIdx.x;
    for (int i = tid; i < NBKT; i += 256) h[i] = hist[i];
    __syncthreads();
    const int base = tid * 16;
    unsigned local = 0;
#pragma unroll
    for (int j = 0; j < 16; ++j) local += h[base + j];
    psum[tid] = local;
    __syncthreads();
    for (int stride = 1; stride < 256; stride <<= 1) {
        unsigned add = (tid + stride < 256) ? psum[tid + stride] : 0u;
        __syncthreads();
        psum[tid] += add;
        __syncthreads();
    }
    unsigned c = (tid + 1 < 256) ? psum[tid + 1] : 0u;  // items in buckets >= (tid+1)*16
    for (int j = 15; j >= 0; --j) {
        unsigned hb = h[base + j];
        if (c < (unsigned)k && c + hb >= (unsigned)k) sB = (unsigned)(base + j);
        c += hb;
    }
    __syncthreads();
    const unsigned B = sB;

    const float4* s4 = (const float4*)scores;
    for (int i = blockIdx.x * 256 + tid; i < n4; i += gridDim.x * 256) {
        float4 v = s4[i];
        const float vv[4] = {v.x, v.y, v.z, v.w};
#pragma unroll
        for (int j = 0; j < 4; ++j) {
            if ((flip(vv[j]) >> 20) >= B) {
                unsigned pos = atomicAdd(cnt, 1u);
                if (pos < CAP) { cand_s[pos] = vv[j]; cand_i[pos] = i * 4 + j; }
            }
        }
    }
}

// ---------------- Pass 4: sort the ~230 candidates, emit top-k -------------------
__global__ __launch_bounds__(256) void k_final(const float* __restrict__ cand_s,
                                               const int* __restrict__ cand_i,
                                               const unsigned* __restrict__ cnt,
                                               int k, float* __restrict__ out) {
    __shared__ float ss[CAP];
    __shared__ int   si[CAP];
    const int tid = threadIdx.x;
    unsigned c = *cnt;
    const int n = (c > CAP) ? CAP : (int)c;
    int N = 64; while (N < n) N <<= 1;   // pow2 >= n (runtime-sized bitonic)
    for (int i = tid; i < N; i += 256) {
        const bool v = i < n;
        ss[i] = v ? cand_s[i] : NEG_INF;
        si[i] = v ? cand_i[i] : 0x7fffffff;
    }
    __syncthreads();
    for (int kk = 2; kk <= N; kk <<= 1) {
        for (int j = kk >> 1; j > 0; j >>= 1) {
            for (int i = tid; i < N; i += 256) {
                int l = i ^ j;
                if (l > i) {
                    float s_i = ss[i], s_l = ss[l];
                    int   d_i = si[i], d_l = si[l];
                    bool sw = ((i & kk) == 0) ? pair_gt(s_l, d_l, s_i, d_i)
                                              : pair_gt(s_i, d_i, s_l, d_l);
                    if (sw) { ss[i] = s_l; si[i] = d_l; ss[l] = s_i; si[l] = d_i; }
                }
            }
            __syncthreads();
        }
    }
    if (tid < k) {
        out[tid]     = ss[tid];
        out[k + tid] = (float)si[tid];   // indices < 2^24: exact in fp32
    }
}

extern "C" void kernel_launch(void* const* d_in, const int* in_sizes, int n_in,
                              void* d_out, int out_size, void* d_ws, size_t ws_size,
                              hipStream_t stream) {
    const float* emb   = (const float*)d_in[0];
    const int*   p_idx = (const int*)d_in[1];
    const int n_items  = in_sizes[0] / 64;   // 1,000,000
    const int k        = out_size / 2;       // 50

    // ws layout (4-byte units)
    float*    scores = (float*)d_ws;
    unsigned* hist   = (unsigned*)(scores + n_items);      // [NBKT]
    unsigned* cnt    = hist + NBKT;                        // candidate counter
    float*    cand_s = (float*)(cnt + 1);
    int*      cand_i = (int*)(cand_s + CAP);

    // zero hist + cnt in one async memset (graph-capture safe)
    hipMemsetAsync(hist, 0, (NBKT + 1) * sizeof(unsigned), stream);

    const int n4 = n_items / 4;
    const int g1 = (n_items + 127) / 128;
    k_gemv   <<<g1,  256, 0, stream>>>(emb, p_idx, n_items, scores);
    k_hist   <<<128, 256, 0, stream>>>(scores, n4, hist);
    k_compact<<<128, 256, 0, stream>>>(scores, n4, hist, k, cnt, cand_s, cand_i);
    k_final  <<<1,   256, 0, stream>>>(cand_s, cand_i, cnt, k, (float*)d_out);
}